// Round 9
// baseline (126.173 us; speedup 1.0000x reference)
//
#include <hip/hip_runtime.h>
#include <hip/hip_bf16.h>

#define SAMPLE 512
#define GDIM   510
#define HID    128
#define LATENT 32
#define HID2   256
#define TB     32      // batch rows per block = two 16-row m-tiles
#define NT     512     // 8 waves

typedef unsigned short u16;
typedef unsigned int   u32;
typedef __attribute__((ext_vector_type(8))) short s16x8;
typedef __attribute__((ext_vector_type(4))) float f32x4;

// packed-weight regions in d_ws (u16 element offsets)
// layout per matrix: [nt][kt][lane 0..63][j 0..7], chunk = 8 u16 = 16 B
#define WGP_OFF   0                         // gather W: N=512(510) K=512
#define W1P_OFF   (WGP_OFF  + 32*16*512)    // w1:  N=128 K=512(510)
#define W2P_OFF   (W1P_OFF  + 8*16*512)     // w2:  N=32  K=128
#define DW1P_OFF  (W2P_OFF  + 2*4*512)      // dw1: N=128 K=32
#define DW2P_OFF  (DW1P_OFF + 8*1*512)      // dw2: N=256 K=128
#define DW3P_OFF  (DW2P_OFF + 16*4*512)     // dw3: N=512 K=256
#define PACK_U16  (DW3P_OFF + 32*8*512)
#define NCHUNK    (PACK_U16 / 8)

__device__ __forceinline__ u16 f2b(float f) {
    union { float f; u32 i; } v; v.f = f;
    return (u16)((v.i + 0x7FFFu + ((v.i >> 16) & 1u)) >> 16);
}

// ---------------- single prologue: build ALL packed weights ----------------
// Dense matrices: transpose-pack. Gather W: per chunk, scan the group's K
// (idx,gw,mask) triples for hits in this chunk's 8-k window (no scatter, no
// cross-kernel ordering dependency).
__global__ __launch_bounds__(256) void build_ws(
    const float* __restrict__ w1, const float* __restrict__ w2,
    const float* __restrict__ dw1, const float* __restrict__ dw2,
    const float* __restrict__ dw3,
    const float* __restrict__ gw, const float* __restrict__ mask,
    const int* __restrict__ idx,
    u16* __restrict__ ws, int G, int K)
{
    int c = blockIdx.x * 256 + threadIdx.x;
    if (c >= NCHUNK) return;
    u16 tmp[8];
    if (c < W1P_OFF / 8) {                 // gather-W region
        int lane = c & 63;
        int kt   = (c >> 6) & 15;
        int nt   = (c >> 6) >> 4;
        int g    = nt * 16 + (lane & 15);
        int k0   = kt * 32 + (lane >> 4) * 8;
        #pragma unroll
        for (int j = 0; j < 8; ++j) tmp[j] = 0;
        if (g < G) {
            const int*   idxr = idx  + (size_t)g * K;
            const float* gwr  = gw   + (size_t)g * K;
            const float* mr   = mask + (size_t)g * K;
            for (int t = 0; t < K; ++t) {
                int j = idxr[t] - k0;
                float m = mr[t];
                if ((unsigned)j < 8u && m > 0.f) tmp[j] = f2b(gwr[t] * m);
            }
        }
        *(s16x8*)(ws + (size_t)c * 8) = *(s16x8*)tmp;
        return;
    }
    const float* W; int Kd, Nd, KT, base;
    if      (c < W2P_OFF / 8)  { W = w1;  Kd = GDIM;   Nd = HID;    KT = 16; base = W1P_OFF / 8; }
    else if (c < DW1P_OFF / 8) { W = w2;  Kd = HID;    Nd = LATENT; KT = 4;  base = W2P_OFF / 8; }
    else if (c < DW2P_OFF / 8) { W = dw1; Kd = LATENT; Nd = HID;    KT = 1;  base = DW1P_OFF / 8; }
    else if (c < DW3P_OFF / 8) { W = dw2; Kd = HID;    Nd = HID2;   KT = 4;  base = DW2P_OFF / 8; }
    else                       { W = dw3; Kd = HID2;   Nd = SAMPLE; KT = 8;  base = DW3P_OFF / 8; }
    int c2   = c - base;
    int lane = c2 & 63;
    int kt   = (c2 >> 6) % KT;
    int nt   = (c2 >> 6) / KT;
    int n    = nt * 16 + (lane & 15);
    int k0   = kt * 32 + (lane >> 4) * 8;
    #pragma unroll
    for (int j = 0; j < 8; ++j) {
        int k = k0 + j;
        float v = (k < Kd && n < Nd) ? W[(size_t)k * Nd + n] : 0.f;
        tmp[j] = f2b(v);
    }
    *(s16x8*)(ws + (size_t)c * 8) = *(s16x8*)tmp;
}

// ---------------- generic MFMA phase: M=32 (2 m-tiles per wave, b reused) ----------------
// N = NTN*16, K = KT*32. 8 waves; wave w owns n-tiles w + 8*i (i<TPW).
template<int KT, int NTN, int TPW>
__device__ __forceinline__ void mfma_phase(
    int wave, int lane,
    const u16* inl, int sin,
    const u16* __restrict__ pW,
    const float* bias,
    u16* outl, int sout)
{
    if (NTN < 8 && wave >= NTN) return;
    const u16* arow0 = inl + (lane & 15) * sin + (lane >> 4) * 8;
    const u16* arow1 = arow0 + 16 * sin;
    f32x4 acc[TPW][2];
    #pragma unroll
    for (int i = 0; i < TPW; ++i) {
        acc[i][0] = (f32x4){0.f, 0.f, 0.f, 0.f};
        acc[i][1] = (f32x4){0.f, 0.f, 0.f, 0.f};
    }
    #pragma unroll
    for (int kt = 0; kt < KT; ++kt) {
        s16x8 a0 = *(const s16x8*)(arow0 + kt * 32);
        s16x8 a1 = *(const s16x8*)(arow1 + kt * 32);
        #pragma unroll
        for (int i = 0; i < TPW; ++i) {
            int nt = wave + 8 * i;
            s16x8 b = *(const s16x8*)(pW + (size_t)((nt * KT + kt) * 64 + lane) * 8);
            acc[i][0] = __builtin_amdgcn_mfma_f32_16x16x32_bf16(a0, b, acc[i][0], 0, 0, 0);
            acc[i][1] = __builtin_amdgcn_mfma_f32_16x16x32_bf16(a1, b, acc[i][1], 0, 0, 0);
        }
    }
    #pragma unroll
    for (int i = 0; i < TPW; ++i) {
        int nt = wave + 8 * i;
        int col = nt * 16 + (lane & 15);
        float bs = bias[col];
        #pragma unroll
        for (int mt = 0; mt < 2; ++mt) {
            #pragma unroll
            for (int r = 0; r < 4; ++r) {
                int row = mt * 16 + (lane >> 4) * 4 + r;
                float v = acc[i][mt][r] + bs;
                outl[row * sout + col] = f2b(v > 0.f ? v : 0.f);
            }
        }
    }
}

// ---------------- fused main kernel (identical to Round-6 proven version) ----------------
// LDS union overlay (u16 offsets):
//   region0 [0,18432): xs [32][520] (phases 0-A) / h2@0 [32][136], zz@4352 [32][40],
//                      d1@5632 [32][136], d2@9984 [32][264] (phases B-F)
//   region1 [18432,35072): h1 [32][520] (phases A-B)
#define XS_OFF 0
#define H2_OFF 0
#define ZZ_OFF 4352
#define D1_OFF 5632
#define D2_OFF 9984
#define H1_OFF 18432
#define SMEM_U16 35072

__global__ __launch_bounds__(NT, 4) void ae_mfma(
    const float* __restrict__ x,
    const float* __restrict__ gb,  const float* __restrict__ b1,
    const float* __restrict__ b2,  const float* __restrict__ db1,
    const float* __restrict__ db2, const float* __restrict__ db3,
    const u16*   __restrict__ ws,
    float* __restrict__ out)
{
    __shared__ __align__(16) u16 smem[SMEM_U16];
    __shared__ float biases[1568];   // gb512 | b1 128 | b2 32 | db1 128 | db2 256 | db3 512
    u16* xs = smem + XS_OFF;
    u16* h1 = smem + H1_OFF;
    u16* h2 = smem + H2_OFF;
    u16* zz = smem + ZZ_OFF;
    u16* d1 = smem + D1_OFF;
    u16* d2 = smem + D2_OFF;

    const int tid  = threadIdx.x;
    const int wave = tid >> 6;
    const int lane = tid & 63;
    const int b0   = blockIdx.x * TB;

    // stage biases (gb zero-padded to 512)
    biases[tid]        = (tid < GDIM) ? gb[tid] : 0.f;
    biases[1056 + tid] = db3[tid];
    if (tid < 128) biases[512 + tid] = b1[tid];
    if (tid < 32)  biases[640 + tid] = b2[tid];
    if (tid < 128) biases[672 + tid] = db1[tid];
    if (tid < 256) biases[800 + tid] = db2[tid];

    // stage x tile -> bf16 LDS
    {
        const float4* xg = (const float4*)(x + (size_t)b0 * SAMPLE);
        #pragma unroll
        for (int it = 0; it < (TB * SAMPLE / 4) / NT; ++it) {
            int v = it * NT + tid;             // float4 index
            float4 f = xg[v];
            int row = v >> 7;                  // 128 float4 per row
            int cp  = (v & 127) * 4;
            u16* p = xs + row * 520 + cp;
            u16 t4[4] = { f2b(f.x), f2b(f.y), f2b(f.z), f2b(f.w) };
            *(unsigned long long*)p = *(unsigned long long*)t4;
        }
    }
    __syncthreads();

    // A: h1 = relu(x @ Wg + gb)        [32,512] x [512,512]
    mfma_phase<16, 32, 4>(wave, lane, xs, 520, ws + WGP_OFF,  biases,       h1, 520);
    __syncthreads();
    // B: h2 = relu(h1 @ w1 + b1)       [32,512] x [512,128]   (h2 overlays dead xs)
    mfma_phase<16, 8, 1>(wave, lane, h1, 520, ws + W1P_OFF,  biases + 512, h2, 136);
    __syncthreads();
    // C: z = relu(h2 @ w2 + b2)        [32,128] x [128,32]
    mfma_phase<4, 2, 1>(wave, lane, h2, 136, ws + W2P_OFF,  biases + 640, zz, 40);
    __syncthreads();
    // D: d1 = relu(z @ dw1 + db1)      [32,32] x [32,128]
    mfma_phase<1, 8, 1>(wave, lane, zz, 40,  ws + DW1P_OFF, biases + 672, d1, 136);
    __syncthreads();
    // E: d2 = relu(d1 @ dw2 + db2)     [32,128] x [128,256]
    mfma_phase<4, 16, 2>(wave, lane, d1, 136, ws + DW2P_OFF, biases + 800, d2, 264);
    __syncthreads();

    // F: out = sigmoid(d2 @ dw3 + db3) [32,256] x [256,512] -> global fp32
    {
        const u16* arow0 = d2 + (lane & 15) * 264 + (lane >> 4) * 8;
        const u16* arow1 = arow0 + 16 * 264;
        const u16* pW = ws + DW3P_OFF;
        f32x4 acc[4][2];
        #pragma unroll
        for (int i = 0; i < 4; ++i) {
            acc[i][0] = (f32x4){0.f, 0.f, 0.f, 0.f};
            acc[i][1] = (f32x4){0.f, 0.f, 0.f, 0.f};
        }
        #pragma unroll
        for (int kt = 0; kt < 8; ++kt) {
            s16x8 a0 = *(const s16x8*)(arow0 + kt * 32);
            s16x8 a1 = *(const s16x8*)(arow1 + kt * 32);
            #pragma unroll
            for (int i = 0; i < 4; ++i) {
                int nt = wave + 8 * i;
                s16x8 b = *(const s16x8*)(pW + (size_t)((nt * 8 + kt) * 64 + lane) * 8);
                acc[i][0] = __builtin_amdgcn_mfma_f32_16x16x32_bf16(a0, b, acc[i][0], 0, 0, 0);
                acc[i][1] = __builtin_amdgcn_mfma_f32_16x16x32_bf16(a1, b, acc[i][1], 0, 0, 0);
            }
        }
        #pragma unroll
        for (int i = 0; i < 4; ++i) {
            int nt = wave + 8 * i;
            int col = nt * 16 + (lane & 15);
            float bs = biases[1056 + col];
            #pragma unroll
            for (int mt = 0; mt < 2; ++mt) {
                #pragma unroll
                for (int r = 0; r < 4; ++r) {
                    int row = mt * 16 + (lane >> 4) * 4 + r;
                    float v = acc[i][mt][r] + bs;
                    out[(size_t)(b0 + row) * SAMPLE + col] = 1.f / (1.f + __expf(-v));
                }
            }
        }
    }
}

extern "C" void kernel_launch(void* const* d_in, const int* in_sizes, int n_in,
                              void* d_out, int out_size, void* d_ws, size_t ws_size,
                              hipStream_t stream) {
    const float* x   = (const float*)d_in[0];
    const float* gw  = (const float*)d_in[1];
    const float* gb  = (const float*)d_in[2];
    const float* w1  = (const float*)d_in[3];
    const float* b1  = (const float*)d_in[4];
    const float* w2  = (const float*)d_in[5];
    const float* b2  = (const float*)d_in[6];
    const float* dw1 = (const float*)d_in[7];
    const float* db1 = (const float*)d_in[8];
    const float* dw2 = (const float*)d_in[9];
    const float* db2 = (const float*)d_in[10];
    const float* dw3 = (const float*)d_in[11];
    const float* db3 = (const float*)d_in[12];
    const int* idx   = (const int*)d_in[13];
    const float* mask= (const float*)d_in[14];
    float* out = (float*)d_out;
    u16* ws = (u16*)d_ws;

    const int B  = in_sizes[0] / SAMPLE;     // 8192
    const int G  = in_sizes[2];              // 510
    const int K  = in_sizes[1] / G;          // 28

    build_ws<<<(NCHUNK + 255) / 256, 256, 0, stream>>>(w1, w2, dw1, dw2, dw3,
                                                       gw, mask, idx, ws, G, K);
    ae_mfma<<<B / TB, NT, 0, stream>>>(x, gb, b1, b2, db1, db2, db3, ws, out);
}

// Round 10
// 119.361 us; speedup vs baseline: 1.0571x; 1.0571x over previous
//
#include <hip/hip_runtime.h>
#include <hip/hip_bf16.h>

#define SAMPLE 512
#define GDIM   510
#define HID    128
#define LATENT 32
#define HID2   256
#define TB     32      // batch rows per block = two 16-row m-tiles
#define NT     512     // 8 waves

typedef unsigned short u16;
typedef unsigned int   u32;
typedef __attribute__((ext_vector_type(8))) short s16x8;
typedef __attribute__((ext_vector_type(4))) float f32x4;

// packed-weight regions in d_ws (u16 element offsets)
// layout per matrix: [nt][kt][lane 0..63][j 0..7], chunk = 8 u16 = 16 B
#define WGP_OFF   0                         // gather W: N=512(510) K=512
#define W1P_OFF   (WGP_OFF  + 32*16*512)    // w1:  N=128 K=512(510)
#define W2P_OFF   (W1P_OFF  + 8*16*512)     // w2:  N=32  K=128
#define DW1P_OFF  (W2P_OFF  + 2*4*512)      // dw1: N=128 K=32
#define DW2P_OFF  (DW1P_OFF + 8*1*512)      // dw2: N=256 K=128
#define DW3P_OFF  (DW2P_OFF + 16*4*512)     // dw3: N=512 K=256
#define PACK_U16  (DW3P_OFF + 32*8*512)
#define NCHUNK    (PACK_U16 / 8)

__device__ __forceinline__ u16 f2b(float f) {
    union { float f; u32 i; } v; v.f = f;
    return (u16)((v.i + 0x7FFFu + ((v.i >> 16) & 1u)) >> 16);
}

// ---------------- single prologue: build ALL packed weights ----------------
__global__ __launch_bounds__(256) void build_ws(
    const float* __restrict__ w1, const float* __restrict__ w2,
    const float* __restrict__ dw1, const float* __restrict__ dw2,
    const float* __restrict__ dw3,
    const float* __restrict__ gw, const float* __restrict__ mask,
    const int* __restrict__ idx,
    u16* __restrict__ ws, int G, int K)
{
    int c = blockIdx.x * 256 + threadIdx.x;
    if (c >= NCHUNK) return;
    u16 tmp[8];
    if (c < W1P_OFF / 8) {                 // gather-W region
        int lane = c & 63;
        int kt   = (c >> 6) & 15;
        int nt   = (c >> 6) >> 4;
        int g    = nt * 16 + (lane & 15);
        int k0   = kt * 32 + (lane >> 4) * 8;
        #pragma unroll
        for (int j = 0; j < 8; ++j) tmp[j] = 0;
        if (g < G) {
            const int*   idxr = idx  + (size_t)g * K;
            const float* gwr  = gw   + (size_t)g * K;
            const float* mr   = mask + (size_t)g * K;
            int t = 0;
            // unrolled x4: independent loads pipeline (scan is latency-bound)
            for (; t + 4 <= K; t += 4) {
                int   j0 = idxr[t]     - k0, j1 = idxr[t + 1] - k0;
                int   j2 = idxr[t + 2] - k0, j3 = idxr[t + 3] - k0;
                float m0 = mr[t],     m1 = mr[t + 1];
                float m2 = mr[t + 2], m3 = mr[t + 3];
                float v0 = gwr[t],     v1 = gwr[t + 1];
                float v2 = gwr[t + 2], v3 = gwr[t + 3];
                if ((unsigned)j0 < 8u && m0 > 0.f) tmp[j0] = f2b(v0 * m0);
                if ((unsigned)j1 < 8u && m1 > 0.f) tmp[j1] = f2b(v1 * m1);
                if ((unsigned)j2 < 8u && m2 > 0.f) tmp[j2] = f2b(v2 * m2);
                if ((unsigned)j3 < 8u && m3 > 0.f) tmp[j3] = f2b(v3 * m3);
            }
            for (; t < K; ++t) {
                int j = idxr[t] - k0;
                float m = mr[t];
                if ((unsigned)j < 8u && m > 0.f) tmp[j] = f2b(gwr[t] * m);
            }
        }
        *(s16x8*)(ws + (size_t)c * 8) = *(s16x8*)tmp;
        return;
    }
    const float* W; int Kd, Nd, KT, base;
    if      (c < W2P_OFF / 8)  { W = w1;  Kd = GDIM;   Nd = HID;    KT = 16; base = W1P_OFF / 8; }
    else if (c < DW1P_OFF / 8) { W = w2;  Kd = HID;    Nd = LATENT; KT = 4;  base = W2P_OFF / 8; }
    else if (c < DW2P_OFF / 8) { W = dw1; Kd = LATENT; Nd = HID;    KT = 1;  base = DW1P_OFF / 8; }
    else if (c < DW3P_OFF / 8) { W = dw2; Kd = HID;    Nd = HID2;   KT = 4;  base = DW2P_OFF / 8; }
    else                       { W = dw3; Kd = HID2;   Nd = SAMPLE; KT = 8;  base = DW3P_OFF / 8; }
    int c2   = c - base;
    int lane = c2 & 63;
    int kt   = (c2 >> 6) % KT;
    int nt   = (c2 >> 6) / KT;
    int n    = nt * 16 + (lane & 15);
    int k0   = kt * 32 + (lane >> 4) * 8;
    #pragma unroll
    for (int j = 0; j < 8; ++j) {
        int k = k0 + j;
        float v = (k < Kd && n < Nd) ? W[(size_t)k * Nd + n] : 0.f;
        tmp[j] = f2b(v);
    }
    *(s16x8*)(ws + (size_t)c * 8) = *(s16x8*)tmp;
}

// ---------------- generic MFMA phase: M=32 (2 m-tiles per wave, b reused) ----------------
// N = NTN*16, K = KT*32. 8 waves; wave w owns n-tiles w + 8*i (i<TPW).
template<int KT, int NTN, int TPW>
__device__ __forceinline__ void mfma_phase(
    int wave, int lane,
    const u16* inl, int sin,
    const u16* __restrict__ pW,
    const float* bias,
    u16* outl, int sout)
{
    if (NTN < 8 && wave >= NTN) return;
    const u16* arow0 = inl + (lane & 15) * sin + (lane >> 4) * 8;
    const u16* arow1 = arow0 + 16 * sin;
    f32x4 acc[TPW][2];
    #pragma unroll
    for (int i = 0; i < TPW; ++i) {
        acc[i][0] = (f32x4){0.f, 0.f, 0.f, 0.f};
        acc[i][1] = (f32x4){0.f, 0.f, 0.f, 0.f};
    }
    #pragma unroll
    for (int kt = 0; kt < KT; ++kt) {
        s16x8 a0 = *(const s16x8*)(arow0 + kt * 32);
        s16x8 a1 = *(const s16x8*)(arow1 + kt * 32);
        #pragma unroll
        for (int i = 0; i < TPW; ++i) {
            int nt = wave + 8 * i;
            s16x8 b = *(const s16x8*)(pW + (size_t)((nt * KT + kt) * 64 + lane) * 8);
            acc[i][0] = __builtin_amdgcn_mfma_f32_16x16x32_bf16(a0, b, acc[i][0], 0, 0, 0);
            acc[i][1] = __builtin_amdgcn_mfma_f32_16x16x32_bf16(a1, b, acc[i][1], 0, 0, 0);
        }
    }
    #pragma unroll
    for (int i = 0; i < TPW; ++i) {
        int nt = wave + 8 * i;
        int col = nt * 16 + (lane & 15);
        float bs = bias[col];
        #pragma unroll
        for (int mt = 0; mt < 2; ++mt) {
            #pragma unroll
            for (int r = 0; r < 4; ++r) {
                int row = mt * 16 + (lane >> 4) * 4 + r;
                float v = acc[i][mt][r] + bs;
                outl[row * sout + col] = f2b(v > 0.f ? v : 0.f);
            }
        }
    }
}

// ---------------- fused main kernel ----------------
// LDS union overlay (u16 offsets):
//   region0 [0,18432): xs [32][520] (phases 0-A) / h2@0 [32][136], zz@4352 [32][40],
//                      d1@5632 [32][136], d2@9984 [32][264] (phases B-F)
//   region1 [18432,35072): h1 [32][520] (phases A-B)
#define XS_OFF 0
#define H2_OFF 0
#define ZZ_OFF 4352
#define D1_OFF 5632
#define D2_OFF 9984
#define H1_OFF 18432
#define SMEM_U16 35072

// (512,2): grid=256 -> 1 block/CU regardless; min-waves=2/EU frees the
// register allocator to 256 VGPRs so the K-loop B-loads pipeline deeper.
__global__ __launch_bounds__(NT, 2) void ae_mfma(
    const float* __restrict__ x,
    const float* __restrict__ gb,  const float* __restrict__ b1,
    const float* __restrict__ b2,  const float* __restrict__ db1,
    const float* __restrict__ db2, const float* __restrict__ db3,
    const u16*   __restrict__ ws,
    float* __restrict__ out)
{
    __shared__ __align__(16) u16 smem[SMEM_U16];
    __shared__ float biases[1568];   // gb512 | b1 128 | b2 32 | db1 128 | db2 256 | db3 512
    u16* xs = smem + XS_OFF;
    u16* h1 = smem + H1_OFF;
    u16* h2 = smem + H2_OFF;
    u16* zz = smem + ZZ_OFF;
    u16* d1 = smem + D1_OFF;
    u16* d2 = smem + D2_OFF;

    const int tid  = threadIdx.x;
    const int wave = tid >> 6;
    const int lane = tid & 63;
    const int b0   = blockIdx.x * TB;

    // stage biases (gb zero-padded to 512)
    biases[tid]        = (tid < GDIM) ? gb[tid] : 0.f;
    biases[1056 + tid] = db3[tid];
    if (tid < 128) biases[512 + tid] = b1[tid];
    if (tid < 32)  biases[640 + tid] = b2[tid];
    if (tid < 128) biases[672 + tid] = db1[tid];
    if (tid < 256) biases[800 + tid] = db2[tid];

    // stage x tile -> bf16 LDS
    {
        const float4* xg = (const float4*)(x + (size_t)b0 * SAMPLE);
        #pragma unroll
        for (int it = 0; it < (TB * SAMPLE / 4) / NT; ++it) {
            int v = it * NT + tid;             // float4 index
            float4 f = xg[v];
            int row = v >> 7;                  // 128 float4 per row
            int cp  = (v & 127) * 4;
            u16* p = xs + row * 520 + cp;
            u16 t4[4] = { f2b(f.x), f2b(f.y), f2b(f.z), f2b(f.w) };
            *(unsigned long long*)p = *(unsigned long long*)t4;
        }
    }
    __syncthreads();

    // A: h1 = relu(x @ Wg + gb)        [32,512] x [512,512]
    mfma_phase<16, 32, 4>(wave, lane, xs, 520, ws + WGP_OFF,  biases,       h1, 520);
    __syncthreads();
    // B: h2 = relu(h1 @ w1 + b1)       [32,512] x [512,128]  (h2 overlays dead xs)
    mfma_phase<16, 8, 1>(wave, lane, h1, 520, ws + W1P_OFF,  biases + 512, h2, 136);
    __syncthreads();

    // C+D fused per-wave: waves 0,1 each own one m-tile; zz write->read is
    // same-wave (compiler lgkmcnt only, no barrier between C and D).
    if (wave < 2) {
        const int mt = wave;
        // C: z = relu(h2 @ w2 + b2)    [16,128] x [128,32]
        {
            const u16* arow = h2 + (mt * 16 + (lane & 15)) * 136 + (lane >> 4) * 8;
            const u16* pW = ws + W2P_OFF;
            f32x4 acc[2];
            acc[0] = (f32x4){0.f, 0.f, 0.f, 0.f};
            acc[1] = (f32x4){0.f, 0.f, 0.f, 0.f};
            #pragma unroll
            for (int kt = 0; kt < 4; ++kt) {
                s16x8 a = *(const s16x8*)(arow + kt * 32);
                #pragma unroll
                for (int i = 0; i < 2; ++i) {
                    s16x8 b = *(const s16x8*)(pW + (size_t)((i * 4 + kt) * 64 + lane) * 8);
                    acc[i] = __builtin_amdgcn_mfma_f32_16x16x32_bf16(a, b, acc[i], 0, 0, 0);
                }
            }
            #pragma unroll
            for (int i = 0; i < 2; ++i) {
                int col = i * 16 + (lane & 15);
                float bs = biases[640 + col];
                #pragma unroll
                for (int r = 0; r < 4; ++r) {
                    int row = mt * 16 + (lane >> 4) * 4 + r;
                    float v = acc[i][r] + bs;
                    zz[row * 40 + col] = f2b(v > 0.f ? v : 0.f);
                }
            }
        }
        // D: d1 = relu(z @ dw1 + db1)  [16,32] x [32,128]
        {
            const u16* arow = zz + (mt * 16 + (lane & 15)) * 40 + (lane >> 4) * 8;
            const u16* pW = ws + DW1P_OFF;
            s16x8 a = *(const s16x8*)(arow);
            f32x4 acc[8];
            #pragma unroll
            for (int i = 0; i < 8; ++i) {
                s16x8 b = *(const s16x8*)(pW + (size_t)(i * 64 + lane) * 8);
                acc[i] = __builtin_amdgcn_mfma_f32_16x16x32_bf16(
                    a, b, (f32x4){0.f, 0.f, 0.f, 0.f}, 0, 0, 0);
            }
            #pragma unroll
            for (int i = 0; i < 8; ++i) {
                int col = i * 16 + (lane & 15);
                float bs = biases[672 + col];
                #pragma unroll
                for (int r = 0; r < 4; ++r) {
                    int row = mt * 16 + (lane >> 4) * 4 + r;
                    float v = acc[i][r] + bs;
                    d1[row * 136 + col] = f2b(v > 0.f ? v : 0.f);
                }
            }
        }
    }
    __syncthreads();

    // E: d2 = relu(d1 @ dw2 + db2)     [32,128] x [128,256]
    mfma_phase<4, 16, 2>(wave, lane, d1, 136, ws + DW2P_OFF, biases + 800, d2, 264);
    __syncthreads();

    // F: out = sigmoid(d2 @ dw3 + db3) [32,256] x [256,512] -> global fp32
    {
        const u16* arow0 = d2 + (lane & 15) * 264 + (lane >> 4) * 8;
        const u16* arow1 = arow0 + 16 * 264;
        const u16* pW = ws + DW3P_OFF;
        f32x4 acc[4][2];
        #pragma unroll
        for (int i = 0; i < 4; ++i) {
            acc[i][0] = (f32x4){0.f, 0.f, 0.f, 0.f};
            acc[i][1] = (f32x4){0.f, 0.f, 0.f, 0.f};
        }
        #pragma unroll
        for (int kt = 0; kt < 8; ++kt) {
            s16x8 a0 = *(const s16x8*)(arow0 + kt * 32);
            s16x8 a1 = *(const s16x8*)(arow1 + kt * 32);
            #pragma unroll
            for (int i = 0; i < 4; ++i) {
                int nt = wave + 8 * i;
                s16x8 b = *(const s16x8*)(pW + (size_t)((nt * 8 + kt) * 64 + lane) * 8);
                acc[i][0] = __builtin_amdgcn_mfma_f32_16x16x32_bf16(a0, b, acc[i][0], 0, 0, 0);
                acc[i][1] = __builtin_amdgcn_mfma_f32_16x16x32_bf16(a1, b, acc[i][1], 0, 0, 0);
            }
        }
        #pragma unroll
        for (int i = 0; i < 4; ++i) {
            int nt = wave + 8 * i;
            int col = nt * 16 + (lane & 15);
            float bs = biases[1056 + col];
            #pragma unroll
            for (int mt = 0; mt < 2; ++mt) {
                #pragma unroll
                for (int r = 0; r < 4; ++r) {
                    int row = mt * 16 + (lane >> 4) * 4 + r;
                    float v = acc[i][mt][r] + bs;
                    out[(size_t)(b0 + row) * SAMPLE + col] = 1.f / (1.f + __expf(-v));
                }
            }
        }
    }
}

extern "C" void kernel_launch(void* const* d_in, const int* in_sizes, int n_in,
                              void* d_out, int out_size, void* d_ws, size_t ws_size,
                              hipStream_t stream) {
    const float* x   = (const float*)d_in[0];
    const float* gw  = (const float*)d_in[1];
    const float* gb  = (const float*)d_in[2];
    const float* w1  = (const float*)d_in[3];
    const float* b1  = (const float*)d_in[4];
    const float* w2  = (const float*)d_in[5];
    const float* b2  = (const float*)d_in[6];
    const float* dw1 = (const float*)d_in[7];
    const float* db1 = (const float*)d_in[8];
    const float* dw2 = (const float*)d_in[9];
    const float* db2 = (const float*)d_in[10];
    const float* dw3 = (const float*)d_in[11];
    const float* db3 = (const float*)d_in[12];
    const int* idx   = (const int*)d_in[13];
    const float* mask= (const float*)d_in[14];
    float* out = (float*)d_out;
    u16* ws = (u16*)d_ws;

    const int B  = in_sizes[0] / SAMPLE;     // 8192
    const int G  = in_sizes[2];              // 510
    const int K  = in_sizes[1] / G;          // 28

    build_ws<<<(NCHUNK + 255) / 256, 256, 0, stream>>>(w1, w2, dw1, dw2, dw3,
                                                       gw, mask, idx, ws, G, K);
    ae_mfma<<<B / TB, NT, 0, stream>>>(x, gb, b1, b2, db1, db2, db3, ws, out);
}